// Round 4
// baseline (3825.326 us; speedup 1.0000x reference)
//
#include <hip/hip_runtime.h>
#include <hip/hip_cooperative_groups.h>

namespace cg = cooperative_groups;

// ---- problem dims (fixed by reference) ----
#define V_ 30000
#define D_ 300
#define DP_ 320
#define T_ 24
#define H_ 256
#define NT_ 6000
#define NU_ 4000
#define N_ 10000
#define F_ 512
#define Z_ 256
#define E_ 80000
#define B_ 2000
#define H1_ 64
#define H2_ 100
#define HEADS_ 8
#define E2_ (E_ + N_)
#define TCH_ 4

typedef __bf16 bf16_t;
typedef bf16_t bf16x8 __attribute__((ext_vector_type(8)));
typedef float  f32x4  __attribute__((ext_vector_type(4)));

// =======================================================================
// LDS-staged 128x128 MFMA GEMM: C = A[M,K] @ B[N,K]^T (+bias)
// Staging: coalesced 32B/thread/matrix/K-step into padded LDS (pitch 40
// bf16 = 80B -> fragment reads are <=2-way bank conflicts = free).
// GM=1: A rows gathered (embedding lookup, row r -> token gnf[(r%NT)*T+t0+r/NT]).
// =======================================================================
template<int GM, bool OUTBF>
__global__ __launch_bounds__(256) void mfma_gemm(
    const bf16_t* __restrict__ A, const bf16_t* __restrict__ B,
    const float* __restrict__ bias, float* __restrict__ Cf,
    bf16_t* __restrict__ Cb, int M, int N, int K, int ldc,
    const int* __restrict__ gtok, int t0)
{
    __shared__ bf16_t As[128 * 40];
    __shared__ bf16_t Bs[128 * 40];
    const int tid  = (int)threadIdx.x;
    const int wave = tid >> 6, lane = tid & 63;
    const int quad = lane >> 4, l16 = lane & 15;
    const int mq = (wave & 1) * 64, nq = (wave >> 1) * 64;
    const int mbase = blockIdx.y * 128, nbase = blockIdx.x * 128;

    const int srow = tid >> 1;          // staging row 0..127
    const int shalf = tid & 1;          // 16-bf16 half of the 32-k tile
    const bf16_t* aptr;
    {
        int r = mbase + srow; if (r >= M) r = M - 1;
        int src = (GM == 1) ? gtok[(r % NT_) * T_ + t0 + (r / NT_)] : r;
        aptr = A + (size_t)src * K;
    }
    const bf16_t* bptr;
    {
        int r = nbase + srow; if (r >= N) r = N - 1;
        bptr = B + (size_t)r * K;
    }

    f32x4 acc[4][4];
#pragma unroll
    for (int mi = 0; mi < 4; mi++)
#pragma unroll
        for (int ni = 0; ni < 4; ni++) acc[mi][ni] = (f32x4){0.f, 0.f, 0.f, 0.f};

    for (int k0 = 0; k0 < K; k0 += 32) {
        __syncthreads();
        bf16x8 a0 = *(const bf16x8*)(aptr + k0 + shalf * 16);
        bf16x8 a1 = *(const bf16x8*)(aptr + k0 + shalf * 16 + 8);
        bf16x8 b0 = *(const bf16x8*)(bptr + k0 + shalf * 16);
        bf16x8 b1 = *(const bf16x8*)(bptr + k0 + shalf * 16 + 8);
        bf16_t* ad = As + srow * 40 + shalf * 16;
        *(bf16x8*)(ad) = a0; *(bf16x8*)(ad + 8) = a1;
        bf16_t* bd = Bs + srow * 40 + shalf * 16;
        *(bf16x8*)(bd) = b0; *(bf16x8*)(bd + 8) = b1;
        __syncthreads();
        bf16x8 afr[4], bfr[4];
#pragma unroll
        for (int mi = 0; mi < 4; mi++)
            afr[mi] = *(const bf16x8*)(As + (mq + mi * 16 + l16) * 40 + quad * 8);
#pragma unroll
        for (int ni = 0; ni < 4; ni++)
            bfr[ni] = *(const bf16x8*)(Bs + (nq + ni * 16 + l16) * 40 + quad * 8);
#pragma unroll
        for (int mi = 0; mi < 4; mi++)
#pragma unroll
            for (int ni = 0; ni < 4; ni++)
                acc[mi][ni] = __builtin_amdgcn_mfma_f32_16x16x32_bf16(
                    afr[mi], bfr[ni], acc[mi][ni], 0, 0, 0);
    }

#pragma unroll
    for (int ni = 0; ni < 4; ni++) {
        int col = nbase + nq + ni * 16 + l16;
        if (col >= N) continue;
        float bv = bias ? bias[col] : 0.f;
#pragma unroll
        for (int mi = 0; mi < 4; mi++)
#pragma unroll
            for (int r = 0; r < 4; r++) {
                int row = mbase + mq + mi * 16 + quad * 4 + r;
                if (row >= M) continue;
                float v = acc[mi][ni][r] + bv;
                if (OUTBF) Cb[(size_t)row * ldc + col] = (bf16_t)v;
                else       Cf[(size_t)row * ldc + col] = v;
            }
    }
}

// =======================================================================
// Cooperative GRU recurrence: nsteps time-steps in ONE launch.
// Block = 128 rows x 32 h-cols. Wh slice (96 rows x 256 k = 48KB) staged
// into LDS ONCE (XOR k-octet swizzle -> conflict-free unpadded reads).
// Per step: gh = h_prev @ Wh^T via MFMA (A-tile staged per k-step),
// gate epilogue with f32 master state, grid.sync() between steps.
// Grid (8,47) = 376 blocks, LDS 57KB -> 2 blocks/CU, co-resident.
// =======================================================================
__global__ __launch_bounds__(256) void gru_rec_coop(
    const bf16_t* __restrict__ Gi, const bf16_t* __restrict__ Wh,
    const float* __restrict__ b_hh, const bf16_t* __restrict__ prev0,
    bf16_t* __restrict__ slots, int slot_mask,
    float* __restrict__ hf, int nsteps)
{
    cg::grid_group gg = cg::this_grid();
    __shared__ bf16_t Whs[96 * 256];
    __shared__ bf16_t As[128 * 32];
    const int tid  = (int)threadIdx.x;
    const int wave = tid >> 6, lane = tid & 63;
    const int quad = lane >> 4, l16 = lane & 15;
    const int rw = wave & 1, cw = wave >> 1;
    const int bm = blockIdx.y * 128;
    const int bn = blockIdx.x * 32;

    // stage Wh slice once (rows l = gate*32 + j  <->  Wh row gate*256+bn+j)
    for (int u = tid; u < 96 * 32; u += 256) {
        int l = u >> 5, seg = u & 31;
        int grow = (l >> 5) * H_ + bn + (l & 31);
        bf16x8 v = *(const bf16x8*)(Wh + (size_t)grow * H_ + seg * 8);
        *(bf16x8*)(Whs + l * H_ + ((seg ^ (l & 7)) * 8)) = v;
    }

    const int srow = tid >> 1;
    const int sg0 = (tid & 1) * 2;
    const int rglob = (bm + srow < NT_) ? bm + srow : NT_ - 1;
    const int col = bn + cw * 16 + l16;
    const float bhr = b_hh[col], bhz = b_hh[H_ + col], bhn = b_hh[2 * H_ + col];

    for (int s = 0; s < nsteps; s++) {
        if (s > 0) gg.sync();
        const bf16_t* hprev = (s == 0) ? prev0
                            : slots + (size_t)((s - 1) & slot_mask) * (NT_ * H_);
        bf16_t* hout = slots + (size_t)(s & slot_mask) * (NT_ * H_);
        const bf16_t* Gis = Gi + (size_t)s * NT_ * (3 * H_);

        f32x4 acc[4][3];
#pragma unroll
        for (int mi = 0; mi < 4; mi++)
#pragma unroll
            for (int g = 0; g < 3; g++) acc[mi][g] = (f32x4){0.f, 0.f, 0.f, 0.f};

        for (int k0 = 0; k0 < H_; k0 += 32) {
            __syncthreads();
#pragma unroll
            for (int j = 0; j < 2; j++) {
                int sg = sg0 + j;
                bf16x8 v = *(const bf16x8*)(hprev + (size_t)rglob * H_ + k0 + sg * 8);
                *(bf16x8*)(As + srow * 32 + ((sg ^ ((srow >> 1) & 3)) * 8)) = v;
            }
            __syncthreads();
            bf16x8 bfr[3], afr[4];
#pragma unroll
            for (int g = 0; g < 3; g++) {
                int l = g * 32 + cw * 16 + l16;
                int sf = (k0 >> 3) + quad;
                bfr[g] = *(const bf16x8*)(Whs + l * H_ + ((sf ^ (l & 7)) * 8));
            }
#pragma unroll
            for (int mi = 0; mi < 4; mi++) {
                int r = rw * 64 + mi * 16 + l16;
                afr[mi] = *(const bf16x8*)(As + r * 32 + ((quad ^ ((r >> 1) & 3)) * 8));
            }
#pragma unroll
            for (int mi = 0; mi < 4; mi++)
#pragma unroll
                for (int g = 0; g < 3; g++)
                    acc[mi][g] = __builtin_amdgcn_mfma_f32_16x16x32_bf16(
                        afr[mi], bfr[g], acc[mi][g], 0, 0, 0);
        }

#pragma unroll
        for (int mi = 0; mi < 4; mi++)
#pragma unroll
            for (int r = 0; r < 4; r++) {
                int m = bm + rw * 64 + mi * 16 + quad * 4 + r;
                if (m >= NT_) continue;
                const bf16_t* gim = Gis + (size_t)m * (3 * H_);
                float ir = (float)gim[col];
                float iz = (float)gim[H_ + col];
                float in_ = (float)gim[2 * H_ + col];
                float hr = acc[mi][0][r] + bhr;
                float hz = acc[mi][1][r] + bhz;
                float hn = acc[mi][2][r] + bhn;
                float rg = 1.f / (1.f + expf(-(ir + hr)));
                float zg = 1.f / (1.f + expf(-(iz + hz)));
                float ng = tanhf(in_ + rg * hn);
                size_t o2 = (size_t)m * H_ + col;
                float hnew = (1.f - zg) * ng + zg * hf[o2];
                hf[o2] = hnew;
                hout[o2] = (bf16_t)hnew;
            }
    }
}

// ---------------- prep: all f32->bf16 conversions in one launch ----------------
struct SegD { const float* src; bf16_t* dst; int rows, cin, cout, transp; };
struct PrepArgs { SegD seg[11]; long long base[12]; int nseg; long long total; };

__global__ void prep_kern(PrepArgs pa)
{
    long long stride = (long long)gridDim.x * blockDim.x;
    for (long long i = (long long)blockIdx.x * blockDim.x + threadIdx.x;
         i < pa.total; i += stride) {
        int k = 0;
        while (k + 1 < pa.nseg && i >= pa.base[k + 1]) k++;
        long long local = i - pa.base[k];
        SegD sg = pa.seg[k];
        int r = (int)(local / sg.cout);
        int c = (int)(local - (long long)r * sg.cout);
        float v;
        if (sg.transp) v = sg.src[(size_t)c * sg.rows + r];
        else           v = (c < sg.cin) ? sg.src[(size_t)r * sg.cin + c] : 0.f;
        sg.dst[local] = (bf16_t)v;
    }
}

// ---------------- small init: zero CSR counters/losses, merge VAE biases ----
__global__ void misc_init(int* __restrict__ deg, int* __restrict__ dcnt,
                          float* __restrict__ loss2, float* __restrict__ b_ml,
                          const float* __restrict__ b_mu, const float* __restrict__ b_lv)
{
    int i = blockIdx.x * blockDim.x + threadIdx.x;
    if (i < N_) { deg[i] = 0; dcnt[i] = 0; }
    if (i < 2 * Z_) b_ml[i] = (i < Z_) ? b_mu[i] : b_lv[i - Z_];
    if (i < 2) loss2[i] = 0.f;
}

__global__ void init_h(const float* __restrict__ h0in, float* __restrict__ h0f,
                       float* __restrict__ h1f, bf16_t* __restrict__ h0b,
                       bf16_t* __restrict__ h1b)
{
    int i = blockIdx.x * blockDim.x + threadIdx.x;
    if (i >= NT_ * H_) return;
    float a = h0in[i], b = h0in[NT_ * H_ + i];
    h0f[i] = a; h1f[i] = b;
    h0b[i] = (bf16_t)a; h1b[i] = (bf16_t)b;
}

// ---------------- CSR build (by dst, self-loops appended) ----------------
__device__ __forceinline__ void edge_sd(const int* __restrict__ ei, int e, int& s, int& d)
{
    if (e < E_) { s = ei[e]; d = ei[E_ + e]; }
    else        { s = d = e - E_; }
}

__global__ void csr_hist(const int* __restrict__ ei, int* __restrict__ deg)
{
    int e = blockIdx.x * blockDim.x + threadIdx.x;
    if (e >= E2_) return;
    int s, d; edge_sd(ei, e, s, d);
    atomicAdd(deg + d, 1);
}

__global__ void csr_scan(const int* __restrict__ deg, int* __restrict__ rowptr)
{
    __shared__ int buf[256];
    __shared__ int carry;
    int tid = (int)threadIdx.x;
    if (tid == 0) { carry = 0; rowptr[0] = 0; }
    __syncthreads();
    for (int c0 = 0; c0 < N_; c0 += 256) {
        int i = c0 + tid;
        buf[tid] = (i < N_) ? deg[i] : 0;
        __syncthreads();
        for (int off = 1; off < 256; off <<= 1) {
            int t = (tid >= off) ? buf[tid - off] : 0;
            __syncthreads();
            buf[tid] += t;
            __syncthreads();
        }
        if (i < N_) rowptr[i + 1] = carry + buf[tid];
        __syncthreads();
        if (tid == 255) carry += buf[255];
        __syncthreads();
    }
}

__global__ void csr_scatter(const int* __restrict__ ei, const int* __restrict__ rowptr,
                            int* __restrict__ dcnt, int* __restrict__ csrc)
{
    int e = blockIdx.x * blockDim.x + threadIdx.x;
    if (e >= E2_) return;
    int s, d; edge_sd(ei, e, s, d);
    int pos = rowptr[d] + atomicAdd(dcnt + d, 1);
    csrc[pos] = s;
}

// ---------------- VAE ----------------
__global__ void vae_z_kl(const float* __restrict__ ml, const float* __restrict__ eps,
                         bf16_t* __restrict__ z_out, float* __restrict__ kl_out)
{
    int idx = blockIdx.x * blockDim.x + threadIdx.x;
    float t = 0.f;
    if (idx < NU_ * Z_) {
        int row = idx >> 8, c = idx & 255;
        float m = ml[(size_t)row * 512 + c];
        float l = ml[(size_t)row * 512 + 256 + c];
        float el = expf(l);
        z_out[idx] = (bf16_t)(m + expf(0.5f * l) * eps[idx]);
        t = -0.5f * (1.f + l - m * m - el);
    }
    __shared__ float red[256];
    red[threadIdx.x] = t;
    __syncthreads();
    for (int s = 128; s > 0; s >>= 1) {
        if ((int)threadIdx.x < s) red[threadIdx.x] += red[threadIdx.x + s];
        __syncthreads();
    }
    if (threadIdx.x == 0) atomicAdd(kl_out, red[0] * (1.f / NU_));
}

__global__ void rec_loss_kern(const float* __restrict__ rec, const float* __restrict__ uf,
                              float* __restrict__ loss_out)
{
    int idx = blockIdx.x * blockDim.x + threadIdx.x;
    float t = 0.f;
    if (idx < NU_ * F_) {
        float d = rec[idx] - uf[idx];
        t = d * d;
    }
    __shared__ float red[256];
    red[threadIdx.x] = t;
    __syncthreads();
    for (int s = 128; s > 0; s >>= 1) {
        if ((int)threadIdx.x < s) red[threadIdx.x] += red[threadIdx.x + s];
        __syncthreads();
    }
    if (threadIdx.x == 0) atomicAdd(loss_out, red[0] * (1.f / (NU_ * F_)));
}

// ---------------- assemble x_in = [hn[:B], z, hn[B:]] (bf16) ----------------
__global__ void assemble_xin(const float* __restrict__ h1, bf16_t* __restrict__ x_in)
{
    int idx = blockIdx.x * blockDim.x + threadIdx.x;
    if (idx >= NT_ * H_) return;
    int row = idx >> 8, col = idx & 255;
    int dst = (row < B_) ? row : (row + NU_);
    x_in[(size_t)dst * H_ + col] = (bf16_t)h1[idx];
}

// ---------------- GAT ----------------
__global__ void gat_attn_coef(const float* __restrict__ xp, const float* __restrict__ a_src,
                              const float* __restrict__ a_dst, float* __restrict__ asn,
                              float* __restrict__ adn, int heads, int C)
{
    int i = blockIdx.x * blockDim.x + threadIdx.x;
    if (i >= N_ * heads) return;
    int node = i / heads, h = i - node * heads;
    const float* x = xp + (size_t)(node * heads + h) * C;
    float s = 0.f, d = 0.f;
    for (int c = 0; c < C; c++) {
        float v = x[c];
        s += v * a_src[h * C + c];
        d += v * a_dst[h * C + c];
    }
    asn[i] = s;
    adn[i] = d;
}

// fused edge-softmax + aggregate, layer 1 (8 heads x 64ch): wave per (dst,head)
__global__ __launch_bounds__(256) void gat_agg1(
    const int* __restrict__ rowptr, const int* __restrict__ csrc,
    const float* __restrict__ asn, const float* __restrict__ adn,
    const float* __restrict__ xp, const float* __restrict__ bias,
    bf16_t* __restrict__ x1out)
{
    int wid = blockIdx.x * 4 + ((int)threadIdx.x >> 6);
    if (wid >= N_ * HEADS_) return;
    int lane = (int)threadIdx.x & 63;
    int d = wid >> 3, h = wid & 7;
    int beg = rowptr[d], end = rowptr[d + 1];
    float adnd = adn[d * 8 + h];
    float mx = -1e30f;
    for (int e = beg; e < end; e++) {
        float l = asn[csrc[e] * 8 + h] + adnd;
        l = (l > 0.f) ? l : 0.2f * l;
        mx = fmaxf(mx, l);
    }
    float den = 0.f, acc = 0.f;
    for (int e = beg; e < end; e++) {
        int s = csrc[e];
        float l = asn[s * 8 + h] + adnd;
        l = (l > 0.f) ? l : 0.2f * l;
        float p = expf(l - mx);
        den += p;
        acc += p * xp[(size_t)s * 512 + h * 64 + lane];
    }
    x1out[(size_t)d * 512 + h * 64 + lane] = (bf16_t)(bias[h * 64 + lane] + acc / den);
}

// fused edge-softmax + aggregate, layer 2 (1 head x 100ch): wave per dst
__global__ __launch_bounds__(256) void gat_agg2(
    const int* __restrict__ rowptr, const int* __restrict__ csrc,
    const float* __restrict__ asn, const float* __restrict__ adn,
    const float* __restrict__ xp, const float* __restrict__ bias,
    float* __restrict__ outp)
{
    int d = blockIdx.x * 4 + ((int)threadIdx.x >> 6);
    if (d >= N_) return;
    int lane = (int)threadIdx.x & 63;
    int beg = rowptr[d], end = rowptr[d + 1];
    float adnd = adn[d];
    float mx = -1e30f;
    for (int e = beg; e < end; e++) {
        float l = asn[csrc[e]] + adnd;
        l = (l > 0.f) ? l : 0.2f * l;
        mx = fmaxf(mx, l);
    }
    float den = 0.f, acc0 = 0.f, acc1 = 0.f;
    for (int e = beg; e < end; e++) {
        int s = csrc[e];
        float l = asn[s] + adnd;
        l = (l > 0.f) ? l : 0.2f * l;
        float p = expf(l - mx);
        den += p;
        acc0 += p * xp[(size_t)s * H2_ + lane];
        if (lane < H2_ - 64) acc1 += p * xp[(size_t)s * H2_ + 64 + lane];
    }
    outp[(size_t)d * H2_ + lane] = bias[lane] + acc0 / den;
    if (lane < H2_ - 64)
        outp[(size_t)d * H2_ + 64 + lane] = bias[64 + lane] + acc1 / den;
}

// ---------------- launcher ----------------
extern "C" void kernel_launch(void* const* d_in, const int* in_sizes, int n_in,
                              void* d_out, int out_size, void* d_ws, size_t ws_size,
                              hipStream_t stream)
{
    const float* user_feats = (const float*)d_in[1];
    const int*   gnf        = (const int*)d_in[2];
    const int*   ei         = (const int*)d_in[3];
    const float* temb       = (const float*)d_in[4];
    const float* w_ih0      = (const float*)d_in[5];
    const float* w_hh0      = (const float*)d_in[6];
    const float* b_ih0      = (const float*)d_in[7];
    const float* b_hh0      = (const float*)d_in[8];
    const float* w_ih1      = (const float*)d_in[9];
    const float* w_hh1      = (const float*)d_in[10];
    const float* b_ih1      = (const float*)d_in[11];
    const float* b_hh1      = (const float*)d_in[12];
    const float* h0in       = (const float*)d_in[13];
    const float* w_mu       = (const float*)d_in[14];
    const float* w_lv       = (const float*)d_in[16];
    const float* w_dec      = (const float*)d_in[18];
    const float* b_dec      = (const float*)d_in[19];
    const float* veps       = (const float*)d_in[20];
    const float* w1         = (const float*)d_in[21];
    const float* a_src1     = (const float*)d_in[22];
    const float* a_dst1     = (const float*)d_in[23];
    const float* b1         = (const float*)d_in[24];
    const float* w2         = (const float*)d_in[25];
    const float* a_src2     = (const float*)d_in[26];
    const float* a_dst2     = (const float*)d_in[27];
    const float* b2         = (const float*)d_in[28];
    const float* b_mu       = (const float*)d_in[15];
    const float* b_lv       = (const float*)d_in[17];
    float* out = (float*)d_out;

    // ---- workspace (byte offsets) ----
    char* wsb = (char*)d_ws;
    bf16_t* temb_bf = (bf16_t*)(wsb + 0);                 // 19,200,000
    bf16_t* Gi_bf   = (bf16_t*)(wsb + 19200000);          // 36,864,000
    //   aliases, VAE phase (before GRU):
    float*  mlbuf   = (float*)(wsb + 19200000);           //  8,192,000
    float*  recb    = (float*)(wsb + 27392000);           //  8,192,000
    //   aliases, GAT phase (after GRU):
    float*  xp1     = (float*)(wsb + 0);                  // 20,480,000
    bf16_t* x1b     = (bf16_t*)(wsb + 20480000);          // 10,240,000
    float*  xp2     = (float*)(wsb + 30720000);           //  4,000,000
    bf16_t* wih0_bf = (bf16_t*)(wsb + 56064000);
    bf16_t* whh0_bf = (bf16_t*)(wsb + 56555520);
    bf16_t* wih1_bf = (bf16_t*)(wsb + 56948736);
    bf16_t* whh1_bf = (bf16_t*)(wsb + 57341952);
    bf16_t* wml_bf  = (bf16_t*)(wsb + 57735168);
    bf16_t* wdec_bf = (bf16_t*)(wsb + 58259456);
    bf16_t* w1t_bf  = (bf16_t*)(wsb + 58521600);
    bf16_t* w2t_bf  = (bf16_t*)(wsb + 58783744);
    float*  b_ml    = (float*)(wsb + 58886144);
    bf16_t* ufeats_bf = (bf16_t*)(wsb + 58888192);
    bf16_t* out0    = (bf16_t*)(wsb + 62984192);          // 4 slots x 3,072,000
    float*  h0f     = (float*)(wsb + 75272192);
    float*  h1f     = (float*)(wsb + 81416192);
    bf16_t* h0b_init = (bf16_t*)(wsb + 87560192);
    bf16_t* h1slots = (bf16_t*)(wsb + 90632192);          // slot0; slot1 follows
    bf16_t* h1s1    = (bf16_t*)(wsb + 93704192);
    bf16_t* xin_bf  = (bf16_t*)(wsb + 96776192);
    int*    deg     = (int*)(wsb + 101896192);
    int*    dcnt    = (int*)(wsb + 101936192);
    int*    rowptr  = (int*)(wsb + 101976192);
    int*    csrc    = (int*)(wsb + 102016256);
    float*  asn1    = (float*)(wsb + 102376256);
    float*  adn1    = (float*)(wsb + 102696256);
    float*  asn2    = (float*)(wsb + 103016256);
    float*  adn2    = (float*)(wsb + 103056256);

    const int TB = 256;
    auto blocks = [](int n) { return (n + 255) / 256; };
    auto ggrid = [](int M, int N) { return dim3((N + 127) / 128, (M + 127) / 128); };

    // ---- prep: all conversions ----
    PrepArgs pa;
    auto seg = [&](int k, const float* s, bf16_t* dst, int rows, int cin, int cout, int tr) {
        pa.seg[k] = SegD{s, dst, rows, cin, cout, tr};
    };
    seg(0, temb, temb_bf, V_, D_, DP_, 0);
    seg(1, w_ih0, wih0_bf, 3 * H_, D_, DP_, 0);
    seg(2, w_hh0, whh0_bf, 3 * H_, H_, H_, 0);
    seg(3, w_ih1, wih1_bf, 3 * H_, H_, H_, 0);
    seg(4, w_hh1, whh1_bf, 3 * H_, H_, H_, 0);
    seg(5, w_mu, wml_bf, Z_, F_, F_, 0);
    seg(6, w_lv, wml_bf + (size_t)Z_ * F_, Z_, F_, F_, 0);
    seg(7, w_dec, wdec_bf, F_, Z_, Z_, 0);
    seg(8, user_feats, ufeats_bf, NU_, F_, F_, 0);
    seg(9, w1, w1t_bf, HEADS_ * H1_, 0, H_, 1);
    seg(10, w2, w2t_bf, H2_, 0, HEADS_ * H1_, 1);
    pa.nseg = 11;
    long long acc = 0;
    for (int k = 0; k < 11; k++) {
        pa.base[k] = acc;
        acc += (long long)pa.seg[k].rows * pa.seg[k].cout;
    }
    pa.base[11] = acc;
    pa.total = acc;
    hipLaunchKernelGGL(prep_kern, dim3(6144), dim3(TB), 0, stream, pa);

    hipLaunchKernelGGL(misc_init, dim3(blocks(N_)), dim3(TB), 0, stream,
                       deg, dcnt, out + N_ * H2_, b_ml, b_mu, b_lv);
    hipLaunchKernelGGL(init_h, dim3(blocks(NT_ * H_)), dim3(TB), 0, stream,
                       h0in, h0f, h1f, h0b_init, h1s1);

    // ---- CSR build ----
    hipLaunchKernelGGL(csr_hist, dim3(blocks(E2_)), dim3(TB), 0, stream, ei, deg);
    hipLaunchKernelGGL(csr_scan, dim3(1), dim3(TB), 0, stream, deg, rowptr);
    hipLaunchKernelGGL(csr_scatter, dim3(blocks(E2_)), dim3(TB), 0, stream,
                       ei, rowptr, dcnt, csrc);

    // ---- VAE ----
    hipLaunchKernelGGL((mfma_gemm<0, false>), ggrid(NU_, 2 * Z_), dim3(TB), 0, stream,
                       ufeats_bf, wml_bf, b_ml, mlbuf, (bf16_t*)nullptr,
                       NU_, 2 * Z_, F_, 2 * Z_, (const int*)nullptr, 0);
    bf16_t* z_bf = xin_bf + (size_t)B_ * H_;
    hipLaunchKernelGGL(vae_z_kl, dim3(blocks(NU_ * Z_)), dim3(TB), 0, stream,
                       mlbuf, veps, z_bf, out + N_ * H2_);
    hipLaunchKernelGGL((mfma_gemm<0, false>), ggrid(NU_, F_), dim3(TB), 0, stream,
                       z_bf, wdec_bf, b_dec, recb, (bf16_t*)nullptr,
                       NU_, F_, Z_, F_, (const int*)nullptr, 0);
    hipLaunchKernelGGL(rec_loss_kern, dim3(blocks(NU_ * F_)), dim3(TB), 0, stream,
                       recb, user_feats, out + N_ * H2_ + 1);

    // ---- 2-layer GRU: batched gi GEMMs + cooperative 4-step recurrence ----
    const int MC = TCH_ * NT_;
    dim3 rgrid(H_ / 32, (NT_ + 127) / 128);   // (8, 47) = 376 blocks
    for (int c = 0; c < T_ / TCH_; c++) {
        int t0 = c * TCH_;
        hipLaunchKernelGGL((mfma_gemm<1, true>), ggrid(MC, 3 * H_), dim3(TB), 0, stream,
                           temb_bf, wih0_bf, b_ih0, (float*)nullptr, Gi_bf,
                           MC, 3 * H_, DP_, 3 * H_, gnf, t0);
        {
            const bf16_t* gi = Gi_bf;
            const bf16_t* wh = whh0_bf;
            const float* bh = b_hh0;
            const bf16_t* prev = (c == 0) ? h0b_init : out0 + (size_t)3 * NT_ * H_;
            bf16_t* slots = out0;
            int mask = 3;
            float* hf = h0f;
            int ns = TCH_;
            void* args[8] = {&gi, &wh, &bh, &prev, &slots, &mask, &hf, &ns};
            hipLaunchCooperativeKernel((void*)gru_rec_coop, rgrid, dim3(TB), args, 0, stream);
        }
        hipLaunchKernelGGL((mfma_gemm<0, true>), ggrid(MC, 3 * H_), dim3(TB), 0, stream,
                           out0, wih1_bf, b_ih1, (float*)nullptr, Gi_bf,
                           MC, 3 * H_, H_, 3 * H_, (const int*)nullptr, 0);
        {
            const bf16_t* gi = Gi_bf;
            const bf16_t* wh = whh1_bf;
            const float* bh = b_hh1;
            const bf16_t* prev = h1s1;
            bf16_t* slots = h1slots;
            int mask = 1;
            float* hf = h1f;
            int ns = TCH_;
            void* args[8] = {&gi, &wh, &bh, &prev, &slots, &mask, &hf, &ns};
            hipLaunchCooperativeKernel((void*)gru_rec_coop, rgrid, dim3(TB), args, 0, stream);
        }
    }

    // ---- assemble x_in ----
    hipLaunchKernelGGL(assemble_xin, dim3(blocks(NT_ * H_)), dim3(TB), 0, stream,
                       h1f, xin_bf);

    // ---- GAT layer 1 ----
    hipLaunchKernelGGL((mfma_gemm<0, false>), ggrid(N_, HEADS_ * H1_), dim3(TB), 0, stream,
                       xin_bf, w1t_bf, (const float*)nullptr, xp1, (bf16_t*)nullptr,
                       N_, HEADS_ * H1_, H_, HEADS_ * H1_, (const int*)nullptr, 0);
    hipLaunchKernelGGL(gat_attn_coef, dim3(blocks(N_ * HEADS_)), dim3(TB), 0, stream,
                       xp1, a_src1, a_dst1, asn1, adn1, HEADS_, H1_);
    hipLaunchKernelGGL(gat_agg1, dim3((N_ * HEADS_ + 3) / 4), dim3(TB), 0, stream,
                       rowptr, csrc, asn1, adn1, xp1, b1, x1b);

    // ---- GAT layer 2 ----
    hipLaunchKernelGGL((mfma_gemm<0, false>), ggrid(N_, H2_), dim3(TB), 0, stream,
                       x1b, w2t_bf, (const float*)nullptr, xp2, (bf16_t*)nullptr,
                       N_, H2_, HEADS_ * H1_, H2_, (const int*)nullptr, 0);
    hipLaunchKernelGGL(gat_attn_coef, dim3(blocks(N_)), dim3(TB), 0, stream,
                       xp2, a_src2, a_dst2, asn2, adn2, 1, H2_);
    hipLaunchKernelGGL(gat_agg2, dim3((N_ + 3) / 4), dim3(TB), 0, stream,
                       rowptr, csrc, asn2, adn2, xp2, b2, out);

    (void)in_sizes; (void)n_in; (void)out_size; (void)ws_size;
}

// Round 5
// 2241.910 us; speedup vs baseline: 1.7063x; 1.7063x over previous
//
#include <hip/hip_runtime.h>

// ---- problem dims (fixed by reference) ----
#define V_ 30000
#define D_ 300
#define DP_ 320
#define T_ 24
#define H_ 256
#define NT_ 6000
#define NU_ 4000
#define N_ 10000
#define F_ 512
#define Z_ 256
#define E_ 80000
#define B_ 2000
#define H1_ 64
#define H2_ 100
#define HEADS_ 8
#define E2_ (E_ + N_)
#define TCH_ 4
#define YB_ 47          // row-blocks per layer in rec grid (47*128 >= 6000)

typedef __bf16 bf16_t;
typedef bf16_t bf16x8 __attribute__((ext_vector_type(8)));
typedef float  f32x4  __attribute__((ext_vector_type(4)));

// =======================================================================
// LDS-staged 128x128 MFMA GEMM: C = A[M,K] @ B[N,K]^T (+bias)
// pitch-40 LDS (80B rows) -> fragment reads <=2-way bank aliasing (free).
// GM=1: A rows gathered (embedding lookup row r -> gnf[(r%NT)*T + t0 + r/NT]).
// =======================================================================
template<int GM, bool OUTBF>
__global__ __launch_bounds__(256) void mfma_gemm(
    const bf16_t* __restrict__ A, const bf16_t* __restrict__ B,
    const float* __restrict__ bias, float* __restrict__ Cf,
    bf16_t* __restrict__ Cb, int M, int N, int K, int ldc,
    const int* __restrict__ gtok, int t0)
{
    __shared__ bf16_t As[128 * 40];
    __shared__ bf16_t Bs[128 * 40];
    const int tid  = (int)threadIdx.x;
    const int wave = tid >> 6, lane = tid & 63;
    const int quad = lane >> 4, l16 = lane & 15;
    const int mq = (wave & 1) * 64, nq = (wave >> 1) * 64;
    const int mbase = blockIdx.y * 128, nbase = blockIdx.x * 128;

    const int srow = tid >> 1;
    const int shalf = tid & 1;
    const bf16_t* aptr;
    {
        int r = mbase + srow; if (r >= M) r = M - 1;
        int src = (GM == 1) ? gtok[(r % NT_) * T_ + t0 + (r / NT_)] : r;
        aptr = A + (size_t)src * K;
    }
    const bf16_t* bptr;
    {
        int r = nbase + srow; if (r >= N) r = N - 1;
        bptr = B + (size_t)r * K;
    }

    f32x4 acc[4][4];
#pragma unroll
    for (int mi = 0; mi < 4; mi++)
#pragma unroll
        for (int ni = 0; ni < 4; ni++) acc[mi][ni] = (f32x4){0.f, 0.f, 0.f, 0.f};

    for (int k0 = 0; k0 < K; k0 += 32) {
        __syncthreads();
        bf16x8 a0 = *(const bf16x8*)(aptr + k0 + shalf * 16);
        bf16x8 a1 = *(const bf16x8*)(aptr + k0 + shalf * 16 + 8);
        bf16x8 b0 = *(const bf16x8*)(bptr + k0 + shalf * 16);
        bf16x8 b1 = *(const bf16x8*)(bptr + k0 + shalf * 16 + 8);
        bf16_t* ad = As + srow * 40 + shalf * 16;
        *(bf16x8*)(ad) = a0; *(bf16x8*)(ad + 8) = a1;
        bf16_t* bd = Bs + srow * 40 + shalf * 16;
        *(bf16x8*)(bd) = b0; *(bf16x8*)(bd + 8) = b1;
        __syncthreads();
        bf16x8 afr[4], bfr[4];
#pragma unroll
        for (int mi = 0; mi < 4; mi++)
            afr[mi] = *(const bf16x8*)(As + (mq + mi * 16 + l16) * 40 + quad * 8);
#pragma unroll
        for (int ni = 0; ni < 4; ni++)
            bfr[ni] = *(const bf16x8*)(Bs + (nq + ni * 16 + l16) * 40 + quad * 8);
#pragma unroll
        for (int mi = 0; mi < 4; mi++)
#pragma unroll
            for (int ni = 0; ni < 4; ni++)
                acc[mi][ni] = __builtin_amdgcn_mfma_f32_16x16x32_bf16(
                    afr[mi], bfr[ni], acc[mi][ni], 0, 0, 0);
    }

#pragma unroll
    for (int ni = 0; ni < 4; ni++) {
        int col = nbase + nq + ni * 16 + l16;
        if (col >= N) continue;
        float bv = bias ? bias[col] : 0.f;
#pragma unroll
        for (int mi = 0; mi < 4; mi++)
#pragma unroll
            for (int r = 0; r < 4; r++) {
                int row = mbase + mq + mi * 16 + quad * 4 + r;
                if (row >= M) continue;
                float v = acc[mi][ni][r] + bv;
                if (OUTBF) Cb[(size_t)row * ldc + col] = (bf16_t)v;
                else       Cf[(size_t)row * ldc + col] = v;
            }
    }
}

// =======================================================================
// Per-step GRU recurrence (NO grid sync — recurrence is per-row local).
// One launch can carry TWO independent layer-steps (L0 step t, L1 step t-4):
// blockIdx.y < YB_ -> lay A; else lay B. Block = 128 rows x 32 h-cols.
// Wh slice (96x256 = 48KB, XOR-swizzled) staged once; h tile staged per
// k-step into pitch-40 LDS. gh = h_prev @ Wh^T by MFMA, gate epilogue.
// =======================================================================
struct RecLay {
    const bf16_t* Gi;      // [NT][768] bf16 (b_ih fused)
    const bf16_t* Wh;      // [768][256]
    const float*  bhh;
    const bf16_t* hprev;   // [NT][256] bf16
    bf16_t*       hout;    // [NT][256] bf16
    float*        hf;      // [NT][256] f32 master
};

__global__ __launch_bounds__(256) void gru_rec_step(RecLay A0, RecLay A1)
{
    const bool second = (blockIdx.y >= YB_);
    const RecLay L = second ? A1 : A0;
    const int byr = second ? (int)blockIdx.y - YB_ : (int)blockIdx.y;

    __shared__ bf16_t Whs[96 * 256];
    __shared__ bf16_t As[128 * 40];
    const int tid  = (int)threadIdx.x;
    const int wave = tid >> 6, lane = tid & 63;
    const int quad = lane >> 4, l16 = lane & 15;
    const int rw = wave & 1, cw = wave >> 1;
    const int bm = byr * 128;
    const int bn = blockIdx.x * 32;

    // stage Wh slice once (row l = gate*32 + j  <->  Wh row gate*256+bn+j)
    for (int u = tid; u < 96 * 32; u += 256) {
        int l = u >> 5, seg = u & 31;
        int grow = (l >> 5) * H_ + bn + (l & 31);
        bf16x8 v = *(const bf16x8*)(L.Wh + (size_t)grow * H_ + seg * 8);
        *(bf16x8*)(Whs + l * H_ + ((seg ^ (l & 7)) * 8)) = v;
    }

    const int srow = tid >> 1;
    const int shalf = tid & 1;
    const int rglob = (bm + srow < NT_) ? bm + srow : NT_ - 1;
    const bf16_t* hp = L.hprev + (size_t)rglob * H_;
    const int col = bn + cw * 16 + l16;
    const float bhr = L.bhh[col], bhz = L.bhh[H_ + col], bhn = L.bhh[2 * H_ + col];

    f32x4 acc[4][3];
#pragma unroll
    for (int mi = 0; mi < 4; mi++)
#pragma unroll
        for (int g = 0; g < 3; g++) acc[mi][g] = (f32x4){0.f, 0.f, 0.f, 0.f};

    for (int k0 = 0; k0 < H_; k0 += 32) {
        __syncthreads();
        bf16x8 v0 = *(const bf16x8*)(hp + k0 + shalf * 16);
        bf16x8 v1 = *(const bf16x8*)(hp + k0 + shalf * 16 + 8);
        bf16_t* ad = As + srow * 40 + shalf * 16;
        *(bf16x8*)(ad) = v0; *(bf16x8*)(ad + 8) = v1;
        __syncthreads();
        bf16x8 bfr[3], afr[4];
#pragma unroll
        for (int g = 0; g < 3; g++) {
            int l = g * 32 + cw * 16 + l16;
            int sf = (k0 >> 3) + quad;
            bfr[g] = *(const bf16x8*)(Whs + l * H_ + ((sf ^ (l & 7)) * 8));
        }
#pragma unroll
        for (int mi = 0; mi < 4; mi++) {
            int r = rw * 64 + mi * 16 + l16;
            afr[mi] = *(const bf16x8*)(As + r * 40 + quad * 8);
        }
#pragma unroll
        for (int mi = 0; mi < 4; mi++)
#pragma unroll
            for (int g = 0; g < 3; g++)
                acc[mi][g] = __builtin_amdgcn_mfma_f32_16x16x32_bf16(
                    afr[mi], bfr[g], acc[mi][g], 0, 0, 0);
    }

#pragma unroll
    for (int mi = 0; mi < 4; mi++)
#pragma unroll
        for (int r = 0; r < 4; r++) {
            int m = bm + rw * 64 + mi * 16 + quad * 4 + r;
            if (m >= NT_) continue;
            const bf16_t* gim = L.Gi + (size_t)m * (3 * H_);
            float ir = (float)gim[col];
            float iz = (float)gim[H_ + col];
            float in_ = (float)gim[2 * H_ + col];
            float hr = acc[mi][0][r] + bhr;
            float hz = acc[mi][1][r] + bhz;
            float hn = acc[mi][2][r] + bhn;
            float rg = 1.f / (1.f + expf(-(ir + hr)));
            float zg = 1.f / (1.f + expf(-(iz + hz)));
            float ng = tanhf(in_ + rg * hn);
            size_t o2 = (size_t)m * H_ + col;
            float hnew = (1.f - zg) * ng + zg * L.hf[o2];
            L.hf[o2] = hnew;
            L.hout[o2] = (bf16_t)hnew;
        }
}

// ---------------- prep: all f32->bf16 conversions in one launch ----------------
struct SegD { const float* src; bf16_t* dst; int rows, cin, cout, transp; };
struct PrepArgs { SegD seg[11]; long long base[12]; int nseg; long long total; };

__global__ void prep_kern(PrepArgs pa)
{
    long long stride = (long long)gridDim.x * blockDim.x;
    for (long long i = (long long)blockIdx.x * blockDim.x + threadIdx.x;
         i < pa.total; i += stride) {
        int k = 0;
        while (k + 1 < pa.nseg && i >= pa.base[k + 1]) k++;
        long long local = i - pa.base[k];
        SegD sg = pa.seg[k];
        int r = (int)(local / sg.cout);
        int c = (int)(local - (long long)r * sg.cout);
        float v;
        if (sg.transp) v = sg.src[(size_t)c * sg.rows + r];
        else           v = (c < sg.cin) ? sg.src[(size_t)r * sg.cin + c] : 0.f;
        sg.dst[local] = (bf16_t)v;
    }
}

__global__ void misc_init(int* __restrict__ deg, int* __restrict__ dcnt,
                          float* __restrict__ loss2, float* __restrict__ b_ml,
                          const float* __restrict__ b_mu, const float* __restrict__ b_lv)
{
    int i = blockIdx.x * blockDim.x + threadIdx.x;
    if (i < N_) { deg[i] = 0; dcnt[i] = 0; }
    if (i < 2 * Z_) b_ml[i] = (i < Z_) ? b_mu[i] : b_lv[i - Z_];
    if (i < 2) loss2[i] = 0.f;
}

__global__ void init_h(const float* __restrict__ h0in, float* __restrict__ h0f,
                       float* __restrict__ h1f, bf16_t* __restrict__ h0b,
                       bf16_t* __restrict__ h1b)
{
    int i = blockIdx.x * blockDim.x + threadIdx.x;
    if (i >= NT_ * H_) return;
    float a = h0in[i], b = h0in[NT_ * H_ + i];
    h0f[i] = a; h1f[i] = b;
    h0b[i] = (bf16_t)a; h1b[i] = (bf16_t)b;
}

// ---------------- CSR build (by dst, self-loops appended) ----------------
__device__ __forceinline__ void edge_sd(const int* __restrict__ ei, int e, int& s, int& d)
{
    if (e < E_) { s = ei[e]; d = ei[E_ + e]; }
    else        { s = d = e - E_; }
}

__global__ void csr_hist(const int* __restrict__ ei, int* __restrict__ deg)
{
    int e = blockIdx.x * blockDim.x + threadIdx.x;
    if (e >= E2_) return;
    int s, d; edge_sd(ei, e, s, d);
    atomicAdd(deg + d, 1);
}

__global__ void csr_scan(const int* __restrict__ deg, int* __restrict__ rowptr)
{
    __shared__ int buf[256];
    __shared__ int carry;
    int tid = (int)threadIdx.x;
    if (tid == 0) { carry = 0; rowptr[0] = 0; }
    __syncthreads();
    for (int c0 = 0; c0 < N_; c0 += 256) {
        int i = c0 + tid;
        buf[tid] = (i < N_) ? deg[i] : 0;
        __syncthreads();
        for (int off = 1; off < 256; off <<= 1) {
            int t = (tid >= off) ? buf[tid - off] : 0;
            __syncthreads();
            buf[tid] += t;
            __syncthreads();
        }
        if (i < N_) rowptr[i + 1] = carry + buf[tid];
        __syncthreads();
        if (tid == 255) carry += buf[255];
        __syncthreads();
    }
}

__global__ void csr_scatter(const int* __restrict__ ei, const int* __restrict__ rowptr,
                            int* __restrict__ dcnt, int* __restrict__ csrc)
{
    int e = blockIdx.x * blockDim.x + threadIdx.x;
    if (e >= E2_) return;
    int s, d; edge_sd(ei, e, s, d);
    int pos = rowptr[d] + atomicAdd(dcnt + d, 1);
    csrc[pos] = s;
}

// ---------------- VAE ----------------
__global__ void vae_z_kl(const float* __restrict__ ml, const float* __restrict__ eps,
                         bf16_t* __restrict__ z_out, float* __restrict__ kl_out)
{
    int idx = blockIdx.x * blockDim.x + threadIdx.x;
    float t = 0.f;
    if (idx < NU_ * Z_) {
        int row = idx >> 8, c = idx & 255;
        float m = ml[(size_t)row * 512 + c];
        float l = ml[(size_t)row * 512 + 256 + c];
        float el = expf(l);
        z_out[idx] = (bf16_t)(m + expf(0.5f * l) * eps[idx]);
        t = -0.5f * (1.f + l - m * m - el);
    }
    __shared__ float red[256];
    red[threadIdx.x] = t;
    __syncthreads();
    for (int s = 128; s > 0; s >>= 1) {
        if ((int)threadIdx.x < s) red[threadIdx.x] += red[threadIdx.x + s];
        __syncthreads();
    }
    if (threadIdx.x == 0) atomicAdd(kl_out, red[0] * (1.f / NU_));
}

__global__ void rec_loss_kern(const float* __restrict__ rec, const float* __restrict__ uf,
                              float* __restrict__ loss_out)
{
    int idx = blockIdx.x * blockDim.x + threadIdx.x;
    float t = 0.f;
    if (idx < NU_ * F_) {
        float d = rec[idx] - uf[idx];
        t = d * d;
    }
    __shared__ float red[256];
    red[threadIdx.x] = t;
    __syncthreads();
    for (int s = 128; s > 0; s >>= 1) {
        if ((int)threadIdx.x < s) red[threadIdx.x] += red[threadIdx.x + s];
        __syncthreads();
    }
    if (threadIdx.x == 0) atomicAdd(loss_out, red[0] * (1.f / (NU_ * F_)));
}

// ---------------- assemble x_in = [hn[:B], z, hn[B:]] (bf16) ----------------
__global__ void assemble_xin(const float* __restrict__ h1, bf16_t* __restrict__ x_in)
{
    int idx = blockIdx.x * blockDim.x + threadIdx.x;
    if (idx >= NT_ * H_) return;
    int row = idx >> 8, col = idx & 255;
    int dst = (row < B_) ? row : (row + NU_);
    x_in[(size_t)dst * H_ + col] = (bf16_t)h1[idx];
}

// ---------------- GAT ----------------
__global__ void gat_attn_coef(const float* __restrict__ xp, const float* __restrict__ a_src,
                              const float* __restrict__ a_dst, float* __restrict__ asn,
                              float* __restrict__ adn, int heads, int C)
{
    int i = blockIdx.x * blockDim.x + threadIdx.x;
    if (i >= N_ * heads) return;
    int node = i / heads, h = i - node * heads;
    const float* x = xp + (size_t)(node * heads + h) * C;
    float s = 0.f, d = 0.f;
    for (int c = 0; c < C; c++) {
        float v = x[c];
        s += v * a_src[h * C + c];
        d += v * a_dst[h * C + c];
    }
    asn[i] = s;
    adn[i] = d;
}

// fused edge-softmax + aggregate, layer 1 (8 heads x 64ch): wave per (dst,head)
__global__ __launch_bounds__(256) void gat_agg1(
    const int* __restrict__ rowptr, const int* __restrict__ csrc,
    const float* __restrict__ asn, const float* __restrict__ adn,
    const float* __restrict__ xp, const float* __restrict__ bias,
    bf16_t* __restrict__ x1out)
{
    int wid = blockIdx.x * 4 + ((int)threadIdx.x >> 6);
    if (wid >= N_ * HEADS_) return;
    int lane = (int)threadIdx.x & 63;
    int d = wid >> 3, h = wid & 7;
    int beg = rowptr[d], end = rowptr[d + 1];
    float adnd = adn[d * 8 + h];
    float mx = -1e30f;
    for (int e = beg; e < end; e++) {
        float l = asn[csrc[e] * 8 + h] + adnd;
        l = (l > 0.f) ? l : 0.2f * l;
        mx = fmaxf(mx, l);
    }
    float den = 0.f, acc = 0.f;
    for (int e = beg; e < end; e++) {
        int s = csrc[e];
        float l = asn[s * 8 + h] + adnd;
        l = (l > 0.f) ? l : 0.2f * l;
        float p = expf(l - mx);
        den += p;
        acc += p * xp[(size_t)s * 512 + h * 64 + lane];
    }
    x1out[(size_t)d * 512 + h * 64 + lane] = (bf16_t)(bias[h * 64 + lane] + acc / den);
}

// fused edge-softmax + aggregate, layer 2 (1 head x 100ch): wave per dst
__global__ __launch_bounds__(256) void gat_agg2(
    const int* __restrict__ rowptr, const int* __restrict__ csrc,
    const float* __restrict__ asn, const float* __restrict__ adn,
    const float* __restrict__ xp, const float* __restrict__ bias,
    float* __restrict__ outp)
{
    int d = blockIdx.x * 4 + ((int)threadIdx.x >> 6);
    if (d >= N_) return;
    int lane = (int)threadIdx.x & 63;
    int beg = rowptr[d], end = rowptr[d + 1];
    float adnd = adn[d];
    float mx = -1e30f;
    for (int e = beg; e < end; e++) {
        float l = asn[csrc[e]] + adnd;
        l = (l > 0.f) ? l : 0.2f * l;
        mx = fmaxf(mx, l);
    }
    float den = 0.f, acc0 = 0.f, acc1 = 0.f;
    for (int e = beg; e < end; e++) {
        int s = csrc[e];
        float l = asn[s] + adnd;
        l = (l > 0.f) ? l : 0.2f * l;
        float p = expf(l - mx);
        den += p;
        acc0 += p * xp[(size_t)s * H2_ + lane];
        if (lane < H2_ - 64) acc1 += p * xp[(size_t)s * H2_ + 64 + lane];
    }
    outp[(size_t)d * H2_ + lane] = bias[lane] + acc0 / den;
    if (lane < H2_ - 64)
        outp[(size_t)d * H2_ + 64 + lane] = bias[64 + lane] + acc1 / den;
}

// ---------------- launcher ----------------
extern "C" void kernel_launch(void* const* d_in, const int* in_sizes, int n_in,
                              void* d_out, int out_size, void* d_ws, size_t ws_size,
                              hipStream_t stream)
{
    const float* user_feats = (const float*)d_in[1];
    const int*   gnf        = (const int*)d_in[2];
    const int*   ei         = (const int*)d_in[3];
    const float* temb       = (const float*)d_in[4];
    const float* w_ih0      = (const float*)d_in[5];
    const float* w_hh0      = (const float*)d_in[6];
    const float* b_ih0      = (const float*)d_in[7];
    const float* b_hh0      = (const float*)d_in[8];
    const float* w_ih1      = (const float*)d_in[9];
    const float* w_hh1      = (const float*)d_in[10];
    const float* b_ih1      = (const float*)d_in[11];
    const float* b_hh1      = (const float*)d_in[12];
    const float* h0in       = (const float*)d_in[13];
    const float* w_mu       = (const float*)d_in[14];
    const float* b_mu       = (const float*)d_in[15];
    const float* w_lv       = (const float*)d_in[16];
    const float* b_lv       = (const float*)d_in[17];
    const float* w_dec      = (const float*)d_in[18];
    const float* b_dec      = (const float*)d_in[19];
    const float* veps       = (const float*)d_in[20];
    const float* w1         = (const float*)d_in[21];
    const float* a_src1     = (const float*)d_in[22];
    const float* a_dst1     = (const float*)d_in[23];
    const float* b1         = (const float*)d_in[24];
    const float* w2         = (const float*)d_in[25];
    const float* a_src2     = (const float*)d_in[26];
    const float* a_dst2     = (const float*)d_in[27];
    const float* b2         = (const float*)d_in[28];
    float* out = (float*)d_out;

    // ---- workspace (byte offsets) ----
    char* wsb = (char*)d_ws;
    bf16_t* temb_bf = (bf16_t*)(wsb + 0);                 // 19.2 MB
    bf16_t* Gi0     = (bf16_t*)(wsb + 19200000);          // 36.86 MB
    bf16_t* Gi1     = (bf16_t*)(wsb + 56064000);          // 36.86 MB (ends 92,928,000)
    //   VAE aliases (before GRU, inside Gi1):
    float*  mlbuf   = (float*)(wsb + 56064000);           // 8.19 MB
    float*  recb    = (float*)(wsb + 64256000);           // 8.19 MB
    //   GAT aliases (after GRU, inside temb/Gi0):
    float*  xp1     = (float*)(wsb + 0);                  // 20.48 MB
    bf16_t* x1b     = (bf16_t*)(wsb + 20480000);          // 10.24 MB
    float*  xp2     = (float*)(wsb + 30720000);           // 4.0 MB
    // persistent weights / state
    bf16_t* wih0_bf = (bf16_t*)(wsb + 92928000);
    bf16_t* whh0_bf = (bf16_t*)(wsb + 93419520);
    bf16_t* wih1_bf = (bf16_t*)(wsb + 93812736);
    bf16_t* whh1_bf = (bf16_t*)(wsb + 94205952);
    bf16_t* wml_bf  = (bf16_t*)(wsb + 94599168);
    bf16_t* wdec_bf = (bf16_t*)(wsb + 95123456);
    bf16_t* w1t_bf  = (bf16_t*)(wsb + 95385600);
    bf16_t* w2t_bf  = (bf16_t*)(wsb + 95648000);
    float*  b_ml    = (float*)(wsb + 95750400);
    bf16_t* ufeats_bf = (bf16_t*)(wsb + 95752448);
    bf16_t* out0    = (bf16_t*)(wsb + 99848448);          // 4 slots x 3,072,000
    float*  h0f     = (float*)(wsb + 112136448);
    float*  h1f     = (float*)(wsb + 118280448);
    bf16_t* h0b_init = (bf16_t*)(wsb + 124424448);
    bf16_t* h1init  = (bf16_t*)(wsb + 127496448);
    bf16_t* h1sA    = (bf16_t*)(wsb + 130568448);
    bf16_t* h1sB    = (bf16_t*)(wsb + 133640448);
    bf16_t* xin_bf  = (bf16_t*)(wsb + 136712448);
    int*    deg     = (int*)(wsb + 141832448);
    int*    dcnt    = (int*)(wsb + 141872448);
    int*    rowptr  = (int*)(wsb + 141912448);
    int*    csrc    = (int*)(wsb + 141952512);
    float*  asn1    = (float*)(wsb + 142312512);
    float*  adn1    = (float*)(wsb + 142632512);
    float*  asn2    = (float*)(wsb + 142952512);
    float*  adn2    = (float*)(wsb + 142992512);

    const int TB = 256;
    auto blocks = [](int n) { return (n + 255) / 256; };
    auto ggrid = [](int M, int N) { return dim3((N + 127) / 128, (M + 127) / 128); };

    // ---- prep ----
    PrepArgs pa;
    auto seg = [&](int k, const float* s, bf16_t* dst, int rows, int cin, int cout, int tr) {
        pa.seg[k] = SegD{s, dst, rows, cin, cout, tr};
    };
    seg(0, temb, temb_bf, V_, D_, DP_, 0);
    seg(1, w_ih0, wih0_bf, 3 * H_, D_, DP_, 0);
    seg(2, w_hh0, whh0_bf, 3 * H_, H_, H_, 0);
    seg(3, w_ih1, wih1_bf, 3 * H_, H_, H_, 0);
    seg(4, w_hh1, whh1_bf, 3 * H_, H_, H_, 0);
    seg(5, w_mu, wml_bf, Z_, F_, F_, 0);
    seg(6, w_lv, wml_bf + (size_t)Z_ * F_, Z_, F_, F_, 0);
    seg(7, w_dec, wdec_bf, F_, Z_, Z_, 0);
    seg(8, user_feats, ufeats_bf, NU_, F_, F_, 0);
    seg(9, w1, w1t_bf, HEADS_ * H1_, 0, H_, 1);
    seg(10, w2, w2t_bf, H2_, 0, HEADS_ * H1_, 1);
    pa.nseg = 11;
    long long acc = 0;
    for (int k = 0; k < 11; k++) {
        pa.base[k] = acc;
        acc += (long long)pa.seg[k].rows * pa.seg[k].cout;
    }
    pa.base[11] = acc;
    pa.total = acc;
    hipLaunchKernelGGL(prep_kern, dim3(6144), dim3(TB), 0, stream, pa);

    hipLaunchKernelGGL(misc_init, dim3(blocks(N_)), dim3(TB), 0, stream,
                       deg, dcnt, out + N_ * H2_, b_ml, b_mu, b_lv);
    hipLaunchKernelGGL(init_h, dim3(blocks(NT_ * H_)), dim3(TB), 0, stream,
                       h0in, h0f, h1f, h0b_init, h1init);

    // ---- CSR build ----
    hipLaunchKernelGGL(csr_hist, dim3(blocks(E2_)), dim3(TB), 0, stream, ei, deg);
    hipLaunchKernelGGL(csr_scan, dim3(1), dim3(TB), 0, stream, deg, rowptr);
    hipLaunchKernelGGL(csr_scatter, dim3(blocks(E2_)), dim3(TB), 0, stream,
                       ei, rowptr, dcnt, csrc);

    // ---- VAE ----
    hipLaunchKernelGGL((mfma_gemm<0, false>), ggrid(NU_, 2 * Z_), dim3(TB), 0, stream,
                       ufeats_bf, wml_bf, b_ml, mlbuf, (bf16_t*)nullptr,
                       NU_, 2 * Z_, F_, 2 * Z_, (const int*)nullptr, 0);
    bf16_t* z_bf = xin_bf + (size_t)B_ * H_;
    hipLaunchKernelGGL(vae_z_kl, dim3(blocks(NU_ * Z_)), dim3(TB), 0, stream,
                       mlbuf, veps, z_bf, out + N_ * H2_);
    hipLaunchKernelGGL((mfma_gemm<0, false>), ggrid(NU_, F_), dim3(TB), 0, stream,
                       z_bf, wdec_bf, b_dec, recb, (bf16_t*)nullptr,
                       NU_, F_, Z_, F_, (const int*)nullptr, 0);
    hipLaunchKernelGGL(rec_loss_kern, dim3(blocks(NU_ * F_)), dim3(TB), 0, stream,
                       recb, user_feats, out + N_ * H2_ + 1);

    // ---- 2-layer GRU: chunked gi GEMMs + paired per-step recurrence ----
    const int MC = TCH_ * NT_;
    auto recL0 = [&](int c, int s) -> RecLay {
        RecLay L;
        L.Gi = Gi0 + (size_t)s * NT_ * 3 * H_;
        L.Wh = whh0_bf; L.bhh = b_hh0;
        L.hprev = (c == 0 && s == 0) ? h0b_init
                : (s == 0) ? out0 + (size_t)3 * NT_ * H_
                           : out0 + (size_t)(s - 1) * NT_ * H_;
        L.hout = out0 + (size_t)s * NT_ * H_;
        L.hf = h0f;
        return L;
    };
    auto recL1 = [&](int c, int s) -> RecLay {
        int t = 4 * c + s;
        RecLay L;
        L.Gi = Gi1 + (size_t)s * NT_ * 3 * H_;
        L.Wh = whh1_bf; L.bhh = b_hh1;
        L.hprev = (t == 0) ? h1init : (((t - 1) & 1) ? h1sB : h1sA);
        L.hout = (t & 1) ? h1sB : h1sA;
        L.hf = h1f;
        return L;
    };

    // chunk 0: L0 only
    hipLaunchKernelGGL((mfma_gemm<1, true>), ggrid(MC, 3 * H_), dim3(TB), 0, stream,
                       temb_bf, wih0_bf, b_ih0, (float*)nullptr, Gi0,
                       MC, 3 * H_, DP_, 3 * H_, gnf, 0);
    for (int s = 0; s < TCH_; s++) {
        RecLay L = recL0(0, s);
        hipLaunchKernelGGL(gru_rec_step, dim3(H_ / 32, YB_), dim3(TB), 0, stream, L, L);
    }
    // chunks 1..5: paired (L0 chunk c, L1 chunk c-1)
    for (int c = 1; c < T_ / TCH_; c++) {
        hipLaunchKernelGGL((mfma_gemm<0, true>), ggrid(MC, 3 * H_), dim3(TB), 0, stream,
                           out0, wih1_bf, b_ih1, (float*)nullptr, Gi1,
                           MC, 3 * H_, H_, 3 * H_, (const int*)nullptr, 0);
        hipLaunchKernelGGL((mfma_gemm<1, true>), ggrid(MC, 3 * H_), dim3(TB), 0, stream,
                           temb_bf, wih0_bf, b_ih0, (float*)nullptr, Gi0,
                           MC, 3 * H_, DP_, 3 * H_, gnf, 4 * c);
        for (int s = 0; s < TCH_; s++) {
            RecLay L0 = recL0(c, s), L1 = recL1(c - 1, s);
            hipLaunchKernelGGL(gru_rec_step, dim3(H_ / 32, 2 * YB_), dim3(TB), 0, stream,
                               L0, L1);
        }
    }
    // final: L1 chunk 5
    hipLaunchKernelGGL((mfma_gemm<0, true>), ggrid(MC, 3 * H_), dim3(TB), 0, stream,
                       out0, wih1_bf, b_ih1, (float*)nullptr, Gi1,
                       MC, 3 * H_, H_, 3 * H_, (const int*)nullptr, 0);
    for (int s = 0; s < TCH_; s++) {
        RecLay L = recL1(T_ / TCH_ - 1, s);
        hipLaunchKernelGGL(gru_rec_step, dim3(H_ / 32, YB_), dim3(TB), 0, stream, L, L);
    }

    // ---- assemble x_in ----
    hipLaunchKernelGGL(assemble_xin, dim3(blocks(NT_ * H_)), dim3(TB), 0, stream,
                       h1f, xin_bf);

    // ---- GAT layer 1 ----
    hipLaunchKernelGGL((mfma_gemm<0, false>), ggrid(N_, HEADS_ * H1_), dim3(TB), 0, stream,
                       xin_bf, w1t_bf, (const float*)nullptr, xp1, (bf16_t*)nullptr,
                       N_, HEADS_ * H1_, H_, HEADS_ * H1_, (const int*)nullptr, 0);
    hipLaunchKernelGGL(gat_attn_coef, dim3(blocks(N_ * HEADS_)), dim3(TB), 0, stream,
                       xp1, a_src1, a_dst1, asn1, adn1, HEADS_, H1_);
    hipLaunchKernelGGL(gat_agg1, dim3((N_ * HEADS_ + 3) / 4), dim3(TB), 0, stream,
                       rowptr, csrc, asn1, adn1, xp1, b1, x1b);

    // ---- GAT layer 2 ----
    hipLaunchKernelGGL((mfma_gemm<0, false>), ggrid(N_, H2_), dim3(TB), 0, stream,
                       x1b, w2t_bf, (const float*)nullptr, xp2, (bf16_t*)nullptr,
                       N_, H2_, HEADS_ * H1_, H2_, (const int*)nullptr, 0);
    hipLaunchKernelGGL(gat_attn_coef, dim3(blocks(N_)), dim3(TB), 0, stream,
                       xp2, a_src2, a_dst2, asn2, adn2, 1, H2_);
    hipLaunchKernelGGL(gat_agg2, dim3((N_ + 3) / 4), dim3(TB), 0, stream,
                       rowptr, csrc, asn2, adn2, xp2, b2, out);

    (void)in_sizes; (void)n_in; (void)out_size; (void)ws_size;
}